// Round 1
// baseline (289.352 us; speedup 1.0000x reference)
//
#include <hip/hip_runtime.h>
#include <hip/hip_bf16.h>

// Sizes fixed by the reference
#define V 50000
#define D 256
#define B 256
#define C 10
#define TWO_D 512
#define VBLK 64
#define NBLK ((V + VBLK - 1) / VBLK)   // 782

typedef __bf16 bf16x8 __attribute__((ext_vector_type(8)));
typedef float f32x4 __attribute__((ext_vector_type(4)));
typedef unsigned short ushort_t;
typedef unsigned int uint_t;

__device__ inline ushort_t f2bf(float f) {
    // round-to-nearest-even fp32 -> bf16 (values are finite here)
    uint_t u = __builtin_bit_cast(uint_t, f);
    uint_t r = (u + 0x7FFFu + ((u >> 16) & 1u)) >> 16;
    return (ushort_t)r;
}

__device__ inline float softplus_f(float x) {
    return (x > 0.f) ? (x + log1pf(__expf(-x))) : log1pf(__expf(x));
}

__device__ inline float wave_reduce(float v) {
    #pragma unroll
    for (int m = 1; m < 64; m <<= 1) v += __shfl_xor(v, m);
    return v;
}

// ---------------------------------------------------------------------------
// K1: per-batch-row block. Encoder + heads + z (fp32->bf16) + KL + ctx logits.
// ---------------------------------------------------------------------------
__global__ __launch_bounds__(512) void k1_encoder(
    const int* __restrict__ center_id, const int* __restrict__ context_ids,
    const float* __restrict__ embeddings,
    const float* __restrict__ prior_means_w, const float* __restrict__ prior_vars_w,
    const float* __restrict__ enc_W, const float* __restrict__ enc_b,
    const float* __restrict__ mean_W, const float* __restrict__ mean_b,
    const float* __restrict__ var_W, const float* __restrict__ var_b,
    const float* __restrict__ vocab_W, const float* __restrict__ vocab_b,
    const float* __restrict__ epsilon,
    ushort_t* __restrict__ z_bf, float* __restrict__ base)
{
    __shared__ __align__(16) float ctx[C][D];
    __shared__ __align__(16) float center[D];
    __shared__ __align__(16) float h[TWO_D];
    __shared__ __align__(16) float zsh[D];
    __shared__ __align__(16) float msh[D];
    __shared__ __align__(16) float vsh[D];
    __shared__ float red[8];
    __shared__ int cids[C];

    const int b = blockIdx.x, tid = threadIdx.x;
    const int cid = center_id[b];

    if (tid < D) center[tid] = embeddings[cid * D + tid];
    if (tid < C) cids[tid] = context_ids[b * C + tid];
    __syncthreads();
    for (int idx = tid; idx < C * D; idx += 512) {
        const int c = idx >> 8, d = idx & 255;
        ctx[c][d] = embeddings[cids[c] * D + d];
    }
    __syncthreads();

    // ---- encoder: h[e] = sum_c relu( encW[e,:D].center + encW[e,D:].ctx_c + b[e] )
    const int e = tid;                               // 0..511
    const float4* wrow = (const float4*)(enc_W + e * TWO_D);
    float a = enc_b[e];
    #pragma unroll 16
    for (int q = 0; q < 64; ++q) {                   // center half, read once
        const float4 w = wrow[q];
        const float4 cc = *(const float4*)&center[q * 4];
        a += w.x * cc.x + w.y * cc.y + w.z * cc.z + w.w * cc.w;
    }
    float tc[C];
    #pragma unroll
    for (int c = 0; c < C; ++c) tc[c] = 0.f;
    #pragma unroll
    for (int d0 = 0; d0 < 4; ++d0) {                 // ctx half: read once, reuse for all 10 c
        float4 w[16];
        #pragma unroll
        for (int q = 0; q < 16; ++q) w[q] = wrow[64 + d0 * 16 + q];
        #pragma unroll
        for (int c = 0; c < C; ++c) {
            float s = 0.f;
            #pragma unroll
            for (int q = 0; q < 16; ++q) {
                const float4 x = *(const float4*)&ctx[c][d0 * 64 + q * 4];
                s += w[q].x * x.x + w[q].y * x.y + w[q].z * x.z + w[q].w * x.w;
            }
            tc[c] += s;
        }
    }
    float he = 0.f;
    #pragma unroll
    for (int c = 0; c < C; ++c) he += fmaxf(a + tc[c], 0.f);
    h[e] = he;
    __syncthreads();

    // ---- heads: threads 0..255 -> mean row i, threads 256..511 -> var row i
    {
        const int i = tid & 255;
        const float* Wr = ((tid < 256) ? mean_W : var_W) + i * TWO_D;
        float s = ((tid < 256) ? mean_b : var_b)[i];
        const float4* w4 = (const float4*)Wr;
        #pragma unroll 16
        for (int q = 0; q < 128; ++q) {
            const float4 w = w4[q];
            const float4 hh = *(const float4*)&h[q * 4];
            s += w.x * hh.x + w.y * hh.y + w.z * hh.z + w.w * hh.w;
        }
        if (tid < 256) msh[i] = s; else vsh[i] = s;
    }
    __syncthreads();

    // ---- z, KL
    float klterm = 0.f;
    if (tid < D) {
        const int i = tid;
        const float m   = msh[i];
        const float var = softplus_f(vsh[i]);
        const float z   = m + __expf(0.5f * var) * epsilon[i];
        zsh[i] = z;
        z_bf[b * D + i] = f2bf(z);
        const float pm = prior_means_w[cid * D + i];
        const float pv = softplus_f(prior_vars_w[cid * D + i]);
        const float dm = pm - m;
        klterm = var / pv + dm * dm / pv - 1.f + __logf(pv) - __logf(var);
    }
    klterm = wave_reduce(klterm);
    const int wid = tid >> 6, lane = tid & 63;
    if (lane == 0) red[wid] = klterm;
    __syncthreads();
    float kl = 0.f;
    if (tid == 0) {
        float t = 0.f;
        #pragma unroll
        for (int wq = 0; wq < 8; ++wq) t += red[wq];
        kl = 0.5f * t;
    }
    __syncthreads();                                  // red[] reused below

    // ---- context logits: sum_c ( z . vocab_W[ctx_c] + vocab_b[ctx_c] )
    float csum = 0.f;
    for (int c0 = 0; c0 < C; c0 += 2) {
        const int half = tid >> 8;                    // 0 or 1
        const int c = c0 + half;
        const int d = tid & 255;
        float p = zsh[d] * vocab_W[cids[c] * D + d];
        p = wave_reduce(p);
        if (lane == 0) red[wid] = p;
        __syncthreads();
        if (tid == 0) {
            csum += red[0] + red[1] + red[2] + red[3] + vocab_b[cids[c0]];
            csum += red[4] + red[5] + red[6] + red[7] + vocab_b[cids[c0 + 1]];
        }
        __syncthreads();
    }
    if (tid == 0) base[b] = csum - kl;
}

// ---------------------------------------------------------------------------
// K3: logits GEMM (bf16 MFMA) + per-(b, v-block) partial sum of exp(logit).
// Block = 256 thr (4 waves). Tile: all 256 b x 64 v. K-loop: 8 steps of 32.
// A (z) frags loaded from global (L2-hot). B (vocab_W) fp32->bf16 reg-staged
// into double-buffered LDS, row stride 40 bf16 (80B) -> conflict-free b128.
// ---------------------------------------------------------------------------
__global__ __launch_bounds__(256) void k3_logits(
    const float* __restrict__ vocab_W, const float* __restrict__ vocab_b,
    const ushort_t* __restrict__ z_bf, float* __restrict__ partial)
{
    __shared__ __align__(16) ushort_t wt[2][64 * 40];

    const int tid = threadIdx.x;
    const int blk = blockIdx.x;
    const int v0 = blk * VBLK;
    const int wid = tid >> 6, lane = tid & 63;
    const int l15 = lane & 15, g = lane >> 4;

    // staging: 512 float4s per 64x32 tile; thread t handles q=t (rows 0..31)
    // and q=t+256 (rows 32..63)
    const int r0 = tid >> 3, kq = tid & 7;
    const int r1 = r0 + 32;
    const int gr0 = min(v0 + r0, V - 1);
    const int gr1 = min(v0 + r1, V - 1);
    const float* src0 = vocab_W + gr0 * D + kq * 4;
    const float* src1 = vocab_W + gr1 * D + kq * 4;
    const int dst0 = r0 * 40 + kq * 4;
    const int dst1 = r1 * 40 + kq * 4;

    // prologue: stage tile 0
    {
        const float4 na = *(const float4*)(src0);
        const float4 nb = *(const float4*)(src1);
        ushort4 pa, pb;
        pa.x = f2bf(na.x); pa.y = f2bf(na.y); pa.z = f2bf(na.z); pa.w = f2bf(na.w);
        pb.x = f2bf(nb.x); pb.y = f2bf(nb.y); pb.z = f2bf(nb.z); pb.w = f2bf(nb.w);
        *(ushort4*)(&wt[0][dst0]) = pa;
        *(ushort4*)(&wt[0][dst1]) = pb;
    }
    __syncthreads();

    f32x4 acc[4][4] = {};
    #pragma unroll 1
    for (int kk = 0; kk < 8; ++kk) {
        const int cur = kk & 1, nxt = cur ^ 1;
        float4 na, nb;
        if (kk < 7) {                                  // issue next-tile loads early
            na = *(const float4*)(src0 + (kk + 1) * 32);
            nb = *(const float4*)(src1 + (kk + 1) * 32);
        }
        bf16x8 A[4], Bf[4];
        #pragma unroll
        for (int bt = 0; bt < 4; ++bt) {
            const int row = wid * 64 + bt * 16 + l15;
            A[bt] = *(const bf16x8*)(z_bf + row * D + kk * 32 + g * 8);
        }
        #pragma unroll
        for (int vt = 0; vt < 4; ++vt) {
            Bf[vt] = *(const bf16x8*)(&wt[cur][(vt * 16 + l15) * 40 + g * 8]);
        }
        #pragma unroll
        for (int bt = 0; bt < 4; ++bt)
            #pragma unroll
            for (int vt = 0; vt < 4; ++vt)
                acc[bt][vt] = __builtin_amdgcn_mfma_f32_16x16x32_bf16(
                    A[bt], Bf[vt], acc[bt][vt], 0, 0, 0);
        if (kk < 7) {
            ushort4 pa, pb;
            pa.x = f2bf(na.x); pa.y = f2bf(na.y); pa.z = f2bf(na.z); pa.w = f2bf(na.w);
            pb.x = f2bf(nb.x); pb.y = f2bf(nb.y); pb.z = f2bf(nb.z); pb.w = f2bf(nb.w);
            *(ushort4*)(&wt[nxt][dst0]) = pa;
            *(ushort4*)(&wt[nxt][dst1]) = pb;
        }
        __syncthreads();
    }

    // epilogue: partial_b = sum over this block's valid v of exp(logit)
    float bias[4];
    bool valid[4];
    #pragma unroll
    for (int vt = 0; vt < 4; ++vt) {
        const int v = v0 + vt * 16 + l15;
        valid[vt] = (v < V);
        bias[vt] = valid[vt] ? vocab_b[v] : 0.f;
    }
    #pragma unroll
    for (int bt = 0; bt < 4; ++bt) {
        #pragma unroll
        for (int r = 0; r < 4; ++r) {
            float s = 0.f;
            #pragma unroll
            for (int vt = 0; vt < 4; ++vt)
                s += valid[vt] ? __expf(acc[bt][vt][r] + bias[vt]) : 0.f;
            #pragma unroll
            for (int m = 1; m < 16; m <<= 1) s += __shfl_xor(s, m);
            if (l15 == 0) {
                const int brow = wid * 64 + bt * 16 + g * 4 + r;   // C/D: row=(lane>>4)*4+reg
                partial[brow * NBLK + blk] = s;
            }
        }
    }
}

// ---------------------------------------------------------------------------
// K4: per-b LSE over the 782 partials; out_b = base_b - C*log(sum)
// ---------------------------------------------------------------------------
__global__ __launch_bounds__(256) void k4_lse(
    const float* __restrict__ partial, const float* __restrict__ base,
    float* __restrict__ outb)
{
    __shared__ float red[4];
    const int b = blockIdx.x, tid = threadIdx.x;
    float s = 0.f;
    for (int i = tid; i < NBLK; i += 256) s += partial[b * NBLK + i];
    s = wave_reduce(s);
    if ((tid & 63) == 0) red[tid >> 6] = s;
    __syncthreads();
    if (tid == 0) {
        const float tot = red[0] + red[1] + red[2] + red[3];
        outb[b] = base[b] - (float)C * __logf(tot);
    }
}

// ---------------------------------------------------------------------------
// K5: final 256 -> 1 reduce
// ---------------------------------------------------------------------------
__global__ __launch_bounds__(256) void k5_final(
    const float* __restrict__ outb, float* __restrict__ out)
{
    __shared__ float red[4];
    const int tid = threadIdx.x;
    float s = outb[tid];
    s = wave_reduce(s);
    if ((tid & 63) == 0) red[tid >> 6] = s;
    __syncthreads();
    if (tid == 0) out[0] = red[0] + red[1] + red[2] + red[3];
}

extern "C" void kernel_launch(void* const* d_in, const int* in_sizes, int n_in,
                              void* d_out, int out_size, void* d_ws, size_t ws_size,
                              hipStream_t stream)
{
    const int*   center_id     = (const int*)d_in[0];
    const int*   context_ids   = (const int*)d_in[1];
    const float* embeddings    = (const float*)d_in[2];
    const float* prior_means_w = (const float*)d_in[3];
    const float* prior_vars_w  = (const float*)d_in[4];
    const float* enc_W         = (const float*)d_in[5];
    const float* enc_b         = (const float*)d_in[6];
    const float* mean_W        = (const float*)d_in[7];
    const float* mean_b        = (const float*)d_in[8];
    const float* var_W         = (const float*)d_in[9];
    const float* var_b         = (const float*)d_in[10];
    const float* vocab_W       = (const float*)d_in[11];
    const float* vocab_b       = (const float*)d_in[12];
    const float* epsilon       = (const float*)d_in[13];

    // workspace layout (all fully rewritten every call)
    ushort_t* z_bf   = (ushort_t*)d_ws;                       // 256*256 bf16 = 128KB
    float*    base   = (float*)((char*)d_ws + B * D * 2);     // 256 f
    float*    outb   = base + B;                              // 256 f
    float*    partial= outb + B;                              // 256*782 f

    hipLaunchKernelGGL(k1_encoder, dim3(B), dim3(512), 0, stream,
                       center_id, context_ids, embeddings, prior_means_w, prior_vars_w,
                       enc_W, enc_b, mean_W, mean_b, var_W, var_b,
                       vocab_W, vocab_b, epsilon, z_bf, base);
    hipLaunchKernelGGL(k3_logits, dim3(NBLK), dim3(256), 0, stream,
                       vocab_W, vocab_b, z_bf, partial);
    hipLaunchKernelGGL(k4_lse, dim3(B), dim3(256), 0, stream, partial, base, outb);
    hipLaunchKernelGGL(k5_final, dim3(1), dim3(256), 0, stream, outb, (float*)d_out);
}

// Round 2
// 74.074 us; speedup vs baseline: 3.9063x; 3.9063x over previous
//
#include <hip/hip_runtime.h>
#include <hip/hip_bf16.h>

// Sizes fixed by the reference
#define V 50000
#define D 256
#define B 256
#define C 10
#define TWO_D 512
#define VBLK 64
#define NBLK ((V + VBLK - 1) / VBLK)   // 782
#define MPAD 4096                      // 256 b * 16 (c padded 10 -> 16)

typedef __bf16 bf16x8 __attribute__((ext_vector_type(8)));
typedef float f32x4 __attribute__((ext_vector_type(4)));
typedef unsigned short ushort_t;
typedef unsigned int uint_t;

__device__ inline ushort_t f2bf(float f) {
    uint_t u = __builtin_bit_cast(uint_t, f);
    uint_t r = (u + 0x7FFFu + ((u >> 16) & 1u)) >> 16;
    return (ushort_t)r;
}

__device__ inline float softplus_f(float x) {
    return (x > 0.f) ? (x + log1pf(__expf(-x))) : log1pf(__expf(x));
}

__device__ inline float wave_reduce(float v) {
    #pragma unroll
    for (int m = 1; m < 64; m <<= 1) v += __shfl_xor(v, m);
    return v;
}

// ---------------------------------------------------------------------------
// K0: build X_bf [4096 x 512]: row m = b*16+c -> [center_b | ctx_{b,c}] bf16,
// rows with c >= 10 zero-filled (masked again in k_enc epilogue).
// ---------------------------------------------------------------------------
__global__ __launch_bounds__(256) void k0_gather(
    const int* __restrict__ center_id, const int* __restrict__ context_ids,
    const float* __restrict__ embeddings, ushort_t* __restrict__ xbf)
{
    const int idx = blockIdx.x * 256 + threadIdx.x;  // float4 index, 0..524287
    const int m = idx >> 7;                          // row 0..4095 (128 float4/row)
    const int q = idx & 127;
    const int k = q * 4;
    const int b = m >> 4, c = m & 15;
    ushort4 o;
    if (k < D) {
        const float4 v = *(const float4*)(embeddings + center_id[b] * D + k);
        o.x = f2bf(v.x); o.y = f2bf(v.y); o.z = f2bf(v.z); o.w = f2bf(v.w);
    } else if (c < C) {
        const float4 v = *(const float4*)(embeddings + context_ids[b * C + c] * D + (k - D));
        o.x = f2bf(v.x); o.y = f2bf(v.y); o.z = f2bf(v.z); o.w = f2bf(v.w);
    } else {
        o.x = 0; o.y = 0; o.z = 0; o.w = 0;
    }
    *(ushort4*)(xbf + idx * 4) = o;
}

// ---------------------------------------------------------------------------
// K_enc: MFMA GEMM out[m][e] = sum_d X[m][d]*enc_W[e][d]; fused epilogue:
// +enc_b, relu, mask c<10, sum over the 16-row (c) tile -> h_bf[b][e].
// Block = 256 thr (4 waves), tile M=64 (4 b) x N=64. Grid = 64*8 = 512.
// ---------------------------------------------------------------------------
__global__ __launch_bounds__(256) void k_enc(
    const float* __restrict__ enc_W, const float* __restrict__ enc_b,
    const ushort_t* __restrict__ xbf, ushort_t* __restrict__ h_bf)
{
    __shared__ __align__(16) ushort_t wt[2][64 * 40];
    const int tid = threadIdx.x;
    const int mblk = blockIdx.x & 63;
    const int nblk = blockIdx.x >> 6;
    const int n0 = nblk * 64;
    const int wid = tid >> 6, lane = tid & 63;
    const int l15 = lane & 15, g = lane >> 4;

    const int r0 = tid >> 3, kq = tid & 7, r1 = r0 + 32;
    const float* src0 = enc_W + (n0 + r0) * TWO_D + kq * 4;
    const float* src1 = enc_W + (n0 + r1) * TWO_D + kq * 4;
    const int dst0 = r0 * 40 + kq * 4;
    const int dst1 = r1 * 40 + kq * 4;

    {   // prologue: stage k-tile 0
        const float4 na = *(const float4*)(src0);
        const float4 nb = *(const float4*)(src1);
        ushort4 pa, pb;
        pa.x = f2bf(na.x); pa.y = f2bf(na.y); pa.z = f2bf(na.z); pa.w = f2bf(na.w);
        pb.x = f2bf(nb.x); pb.y = f2bf(nb.y); pb.z = f2bf(nb.z); pb.w = f2bf(nb.w);
        *(ushort4*)(&wt[0][dst0]) = pa;
        *(ushort4*)(&wt[0][dst1]) = pb;
    }
    __syncthreads();

    const int rowA = mblk * 64 + wid * 16 + l15;
    f32x4 acc[4] = {};
    #pragma unroll 1
    for (int kk = 0; kk < 16; ++kk) {
        const int cur = kk & 1, nxt = cur ^ 1;
        float4 na, nb;
        if (kk < 15) {
            na = *(const float4*)(src0 + (kk + 1) * 32);
            nb = *(const float4*)(src1 + (kk + 1) * 32);
        }
        const bf16x8 A = *(const bf16x8*)(xbf + rowA * TWO_D + kk * 32 + g * 8);
        bf16x8 Bf[4];
        #pragma unroll
        for (int vt = 0; vt < 4; ++vt)
            Bf[vt] = *(const bf16x8*)(&wt[cur][(vt * 16 + l15) * 40 + g * 8]);
        #pragma unroll
        for (int vt = 0; vt < 4; ++vt)
            acc[vt] = __builtin_amdgcn_mfma_f32_16x16x32_bf16(A, Bf[vt], acc[vt], 0, 0, 0);
        if (kk < 15) {
            ushort4 pa, pb;
            pa.x = f2bf(na.x); pa.y = f2bf(na.y); pa.z = f2bf(na.z); pa.w = f2bf(na.w);
            pb.x = f2bf(nb.x); pb.y = f2bf(nb.y); pb.z = f2bf(nb.z); pb.w = f2bf(nb.w);
            *(ushort4*)(&wt[nxt][dst0]) = pa;
            *(ushort4*)(&wt[nxt][dst1]) = pb;
        }
        __syncthreads();
    }

    // epilogue: h[b][e] = sum_{c<10} relu(out + enc_b[e]); b = mblk*4 + wid
    const int b = mblk * 4 + wid;
    #pragma unroll
    for (int vt = 0; vt < 4; ++vt) {
        const int j = n0 + vt * 16 + l15;
        const float bias = enc_b[j];
        float s = 0.f;
        #pragma unroll
        for (int r = 0; r < 4; ++r) {
            const int c = g * 4 + r;                 // C/D: row = (lane>>4)*4 + reg
            const float vv = acc[vt][r] + bias;
            s += (c < C) ? fmaxf(vv, 0.f) : 0.f;
        }
        s += __shfl_xor(s, 16);
        s += __shfl_xor(s, 32);
        if (g == 0) h_bf[b * TWO_D + j] = f2bf(s);
    }
}

// ---------------------------------------------------------------------------
// K_heads: MFMA GEMM mv[b][j] = sum_e h[b][e]*W[j][e] + bias[j], where
// j<256 -> mean_W/mean_b, j>=256 -> var_W/var_b. Tile M=64 x N=64.
// Grid = 4*8 = 32 (mblk = blockIdx&3, nblk = blockIdx>>2).
// ---------------------------------------------------------------------------
__global__ __launch_bounds__(256) void k_heads(
    const float* __restrict__ mean_W, const float* __restrict__ mean_b,
    const float* __restrict__ var_W, const float* __restrict__ var_b,
    const ushort_t* __restrict__ h_bf, float* __restrict__ mv)
{
    __shared__ __align__(16) ushort_t wt[2][64 * 40];
    const int tid = threadIdx.x;
    const int mblk = blockIdx.x & 3;
    const int nblk = blockIdx.x >> 2;
    const int n0 = nblk * 64;
    const float* Wsrc = (nblk < 4) ? mean_W : var_W;
    const float* bsrc = (nblk < 4) ? mean_b : var_b;
    const int nloc = (nblk & 3) * 64;
    const int wid = tid >> 6, lane = tid & 63;
    const int l15 = lane & 15, g = lane >> 4;

    const int r0 = tid >> 3, kq = tid & 7, r1 = r0 + 32;
    const float* src0 = Wsrc + (nloc + r0) * TWO_D + kq * 4;
    const float* src1 = Wsrc + (nloc + r1) * TWO_D + kq * 4;
    const int dst0 = r0 * 40 + kq * 4;
    const int dst1 = r1 * 40 + kq * 4;

    {
        const float4 na = *(const float4*)(src0);
        const float4 nb = *(const float4*)(src1);
        ushort4 pa, pb;
        pa.x = f2bf(na.x); pa.y = f2bf(na.y); pa.z = f2bf(na.z); pa.w = f2bf(na.w);
        pb.x = f2bf(nb.x); pb.y = f2bf(nb.y); pb.z = f2bf(nb.z); pb.w = f2bf(nb.w);
        *(ushort4*)(&wt[0][dst0]) = pa;
        *(ushort4*)(&wt[0][dst1]) = pb;
    }
    __syncthreads();

    const int rowA = mblk * 64 + wid * 16 + l15;
    f32x4 acc[4] = {};
    #pragma unroll 1
    for (int kk = 0; kk < 16; ++kk) {
        const int cur = kk & 1, nxt = cur ^ 1;
        float4 na, nb;
        if (kk < 15) {
            na = *(const float4*)(src0 + (kk + 1) * 32);
            nb = *(const float4*)(src1 + (kk + 1) * 32);
        }
        const bf16x8 A = *(const bf16x8*)(h_bf + rowA * TWO_D + kk * 32 + g * 8);
        bf16x8 Bf[4];
        #pragma unroll
        for (int vt = 0; vt < 4; ++vt)
            Bf[vt] = *(const bf16x8*)(&wt[cur][(vt * 16 + l15) * 40 + g * 8]);
        #pragma unroll
        for (int vt = 0; vt < 4; ++vt)
            acc[vt] = __builtin_amdgcn_mfma_f32_16x16x32_bf16(A, Bf[vt], acc[vt], 0, 0, 0);
        if (kk < 15) {
            ushort4 pa, pb;
            pa.x = f2bf(na.x); pa.y = f2bf(na.y); pa.z = f2bf(na.z); pa.w = f2bf(na.w);
            pb.x = f2bf(nb.x); pb.y = f2bf(nb.y); pb.z = f2bf(nb.z); pb.w = f2bf(nb.w);
            *(ushort4*)(&wt[nxt][dst0]) = pa;
            *(ushort4*)(&wt[nxt][dst1]) = pb;
        }
        __syncthreads();
    }

    const int rowBase = mblk * 64 + wid * 16;
    #pragma unroll
    for (int vt = 0; vt < 4; ++vt) {
        const int col = n0 + vt * 16 + l15;
        const float bias = bsrc[nloc + vt * 16 + l15];
        #pragma unroll
        for (int r = 0; r < 4; ++r) {
            const int row = rowBase + g * 4 + r;
            mv[row * TWO_D + col] = acc[vt][r] + bias;
        }
    }
}

// ---------------------------------------------------------------------------
// K_z: per-b: softplus, z (fp32 -> bf16), KL, ctx-logit sum via z . (sum_c w_c)
// ---------------------------------------------------------------------------
__global__ __launch_bounds__(256) void k_z(
    const int* __restrict__ center_id, const int* __restrict__ context_ids,
    const float* __restrict__ prior_means_w, const float* __restrict__ prior_vars_w,
    const float* __restrict__ vocab_W, const float* __restrict__ vocab_b,
    const float* __restrict__ epsilon, const float* __restrict__ mv,
    ushort_t* __restrict__ z_bf, float* __restrict__ base)
{
    __shared__ float red[8];
    __shared__ int cids[C];
    const int b = blockIdx.x, tid = threadIdx.x;
    const int cid = center_id[b];
    if (tid < C) cids[tid] = context_ids[b * C + tid];
    __syncthreads();

    const int i = tid;
    const float mean = mv[b * TWO_D + i];
    const float a    = mv[b * TWO_D + D + i];
    const float var  = softplus_f(a);
    const float z    = mean + __expf(0.5f * var) * epsilon[i];
    z_bf[b * D + i]  = f2bf(z);

    const float pm = prior_means_w[cid * D + i];
    const float pv = softplus_f(prior_vars_w[cid * D + i]);
    const float dm = pm - mean;
    float klt = var / pv + dm * dm / pv - 1.f + __logf(pv) - __logf(var);

    float wsum = 0.f;
    #pragma unroll
    for (int c = 0; c < C; ++c) wsum += vocab_W[cids[c] * D + i];
    float p = z * wsum;

    klt = wave_reduce(klt);
    p = wave_reduce(p);
    const int wid = tid >> 6, lane = tid & 63;
    if (lane == 0) { red[wid] = klt; red[4 + wid] = p; }
    __syncthreads();
    if (tid == 0) {
        const float kl = 0.5f * (red[0] + red[1] + red[2] + red[3]);
        float cs = red[4] + red[5] + red[6] + red[7];
        #pragma unroll
        for (int c = 0; c < C; ++c) cs += vocab_b[cids[c]];
        base[b] = cs - kl;
    }
}

// ---------------------------------------------------------------------------
// K3: logits GEMM (bf16 MFMA) + per-(b, v-block) partial sum of exp(logit).
// (unchanged from round 1 — proven correct)
// ---------------------------------------------------------------------------
__global__ __launch_bounds__(256) void k3_logits(
    const float* __restrict__ vocab_W, const float* __restrict__ vocab_b,
    const ushort_t* __restrict__ z_bf, float* __restrict__ partial)
{
    __shared__ __align__(16) ushort_t wt[2][64 * 40];

    const int tid = threadIdx.x;
    const int blk = blockIdx.x;
    const int v0 = blk * VBLK;
    const int wid = tid >> 6, lane = tid & 63;
    const int l15 = lane & 15, g = lane >> 4;

    const int r0 = tid >> 3, kq = tid & 7;
    const int r1 = r0 + 32;
    const int gr0 = min(v0 + r0, V - 1);
    const int gr1 = min(v0 + r1, V - 1);
    const float* src0 = vocab_W + gr0 * D + kq * 4;
    const float* src1 = vocab_W + gr1 * D + kq * 4;
    const int dst0 = r0 * 40 + kq * 4;
    const int dst1 = r1 * 40 + kq * 4;

    {
        const float4 na = *(const float4*)(src0);
        const float4 nb = *(const float4*)(src1);
        ushort4 pa, pb;
        pa.x = f2bf(na.x); pa.y = f2bf(na.y); pa.z = f2bf(na.z); pa.w = f2bf(na.w);
        pb.x = f2bf(nb.x); pb.y = f2bf(nb.y); pb.z = f2bf(nb.z); pb.w = f2bf(nb.w);
        *(ushort4*)(&wt[0][dst0]) = pa;
        *(ushort4*)(&wt[0][dst1]) = pb;
    }
    __syncthreads();

    f32x4 acc[4][4] = {};
    #pragma unroll 1
    for (int kk = 0; kk < 8; ++kk) {
        const int cur = kk & 1, nxt = cur ^ 1;
        float4 na, nb;
        if (kk < 7) {
            na = *(const float4*)(src0 + (kk + 1) * 32);
            nb = *(const float4*)(src1 + (kk + 1) * 32);
        }
        bf16x8 A[4], Bf[4];
        #pragma unroll
        for (int bt = 0; bt < 4; ++bt) {
            const int row = wid * 64 + bt * 16 + l15;
            A[bt] = *(const bf16x8*)(z_bf + row * D + kk * 32 + g * 8);
        }
        #pragma unroll
        for (int vt = 0; vt < 4; ++vt) {
            Bf[vt] = *(const bf16x8*)(&wt[cur][(vt * 16 + l15) * 40 + g * 8]);
        }
        #pragma unroll
        for (int bt = 0; bt < 4; ++bt)
            #pragma unroll
            for (int vt = 0; vt < 4; ++vt)
                acc[bt][vt] = __builtin_amdgcn_mfma_f32_16x16x32_bf16(
                    A[bt], Bf[vt], acc[bt][vt], 0, 0, 0);
        if (kk < 7) {
            ushort4 pa, pb;
            pa.x = f2bf(na.x); pa.y = f2bf(na.y); pa.z = f2bf(na.z); pa.w = f2bf(na.w);
            pb.x = f2bf(nb.x); pb.y = f2bf(nb.y); pb.z = f2bf(nb.z); pb.w = f2bf(nb.w);
            *(ushort4*)(&wt[nxt][dst0]) = pa;
            *(ushort4*)(&wt[nxt][dst1]) = pb;
        }
        __syncthreads();
    }

    float bias[4];
    bool valid[4];
    #pragma unroll
    for (int vt = 0; vt < 4; ++vt) {
        const int v = v0 + vt * 16 + l15;
        valid[vt] = (v < V);
        bias[vt] = valid[vt] ? vocab_b[v] : 0.f;
    }
    #pragma unroll
    for (int bt = 0; bt < 4; ++bt) {
        #pragma unroll
        for (int r = 0; r < 4; ++r) {
            float s = 0.f;
            #pragma unroll
            for (int vt = 0; vt < 4; ++vt)
                s += valid[vt] ? __expf(acc[bt][vt][r] + bias[vt]) : 0.f;
            #pragma unroll
            for (int m = 1; m < 16; m <<= 1) s += __shfl_xor(s, m);
            if (l15 == 0) {
                const int brow = wid * 64 + bt * 16 + g * 4 + r;
                partial[brow * NBLK + blk] = s;
            }
        }
    }
}

// ---------------------------------------------------------------------------
// K4: per-b LSE over the 782 partials; out_b = base_b - C*log(sum)
// ---------------------------------------------------------------------------
__global__ __launch_bounds__(256) void k4_lse(
    const float* __restrict__ partial, const float* __restrict__ base,
    float* __restrict__ outb)
{
    __shared__ float red[4];
    const int b = blockIdx.x, tid = threadIdx.x;
    float s = 0.f;
    for (int i = tid; i < NBLK; i += 256) s += partial[b * NBLK + i];
    s = wave_reduce(s);
    if ((tid & 63) == 0) red[tid >> 6] = s;
    __syncthreads();
    if (tid == 0) {
        const float tot = red[0] + red[1] + red[2] + red[3];
        outb[b] = base[b] - (float)C * __logf(tot);
    }
}

// ---------------------------------------------------------------------------
// K5: final 256 -> 1 reduce
// ---------------------------------------------------------------------------
__global__ __launch_bounds__(256) void k5_final(
    const float* __restrict__ outb, float* __restrict__ out)
{
    __shared__ float red[4];
    const int tid = threadIdx.x;
    float s = outb[tid];
    s = wave_reduce(s);
    if ((tid & 63) == 0) red[tid >> 6] = s;
    __syncthreads();
    if (tid == 0) out[0] = red[0] + red[1] + red[2] + red[3];
}

extern "C" void kernel_launch(void* const* d_in, const int* in_sizes, int n_in,
                              void* d_out, int out_size, void* d_ws, size_t ws_size,
                              hipStream_t stream)
{
    const int*   center_id     = (const int*)d_in[0];
    const int*   context_ids   = (const int*)d_in[1];
    const float* embeddings    = (const float*)d_in[2];
    const float* prior_means_w = (const float*)d_in[3];
    const float* prior_vars_w  = (const float*)d_in[4];
    const float* enc_W         = (const float*)d_in[5];
    const float* enc_b         = (const float*)d_in[6];
    const float* mean_W        = (const float*)d_in[7];
    const float* mean_b        = (const float*)d_in[8];
    const float* var_W         = (const float*)d_in[9];
    const float* var_b         = (const float*)d_in[10];
    const float* vocab_W       = (const float*)d_in[11];
    const float* vocab_b       = (const float*)d_in[12];
    const float* epsilon       = (const float*)d_in[13];

    // workspace layout (all fully rewritten every call)
    char* ws = (char*)d_ws;
    ushort_t* xbf     = (ushort_t*)ws;                            // 4096*512*2 = 4 MB
    ws += (size_t)MPAD * TWO_D * 2;
    ushort_t* h_bf    = (ushort_t*)ws;                            // 256*512*2 = 256 KB
    ws += (size_t)B * TWO_D * 2;
    float*    mv      = (float*)ws;                               // 256*512*4 = 512 KB
    ws += (size_t)B * TWO_D * 4;
    ushort_t* z_bf    = (ushort_t*)ws;                            // 256*256*2 = 128 KB
    ws += (size_t)B * D * 2;
    float*    base    = (float*)ws;  ws += B * 4;
    float*    outb    = (float*)ws;  ws += B * 4;
    float*    partial = (float*)ws;                               // 256*782*4 = 800 KB

    hipLaunchKernelGGL(k0_gather, dim3(2048), dim3(256), 0, stream,
                       center_id, context_ids, embeddings, xbf);
    hipLaunchKernelGGL(k_enc, dim3(512), dim3(256), 0, stream,
                       enc_W, enc_b, xbf, h_bf);
    hipLaunchKernelGGL(k_heads, dim3(32), dim3(256), 0, stream,
                       mean_W, mean_b, var_W, var_b, h_bf, mv);
    hipLaunchKernelGGL(k_z, dim3(B), dim3(256), 0, stream,
                       center_id, context_ids, prior_means_w, prior_vars_w,
                       vocab_W, vocab_b, epsilon, mv, z_bf, base);
    hipLaunchKernelGGL(k3_logits, dim3(NBLK), dim3(256), 0, stream,
                       vocab_W, vocab_b, z_bf, partial);
    hipLaunchKernelGGL(k4_lse, dim3(B), dim3(256), 0, stream, partial, base, outb);
    hipLaunchKernelGGL(k5_final, dim3(1), dim3(256), 0, stream, outb, (float*)d_out);
}